// Round 1
// baseline (8196.445 us; speedup 1.0000x reference)
//
#include <hip/hip_runtime.h>
#include <math.h>

// ---- problem constants ----
#define BB 64
#define SS 512
#define II 1024
#define HH 1024

typedef _Float16 half8  __attribute__((ext_vector_type(8)));
typedef _Float16 half4_t __attribute__((ext_vector_type(4)));
typedef float    float4_t __attribute__((ext_vector_type(4)));

// ---- workspace layout (bytes) ----
#define XH_OFF   0u            // fp16 x, (S,B,I) layout: 67108864 B
#define WIH_OFF  67108864u     // fp16 W_ih [H][I]: 2097152 B
#define WHH_OFF  69206016u     // fp16 W_hh [H][H]: 2097152 B
#define HBUF_OFF 71303168u     // fp16 h double buffer [2][64][1024]: 262144 B
#define FLG_OFF  71565312u     // 32 per-WG flags, padded to 128 B stride (4 KB)

__device__ __forceinline__ void load_lds16(const void* g, void* l) {
  __builtin_amdgcn_global_load_lds(
      (const __attribute__((address_space(1))) void*)g,
      (__attribute__((address_space(3))) void*)l, 16, 0, 0);
}

// ============================================================
// Kernel 0: convert x -> fp16 time-major, weights -> fp16, zero flags
// ============================================================
__global__ __launch_bounds__(256) void convert_kernel(
    const float* __restrict__ x, const float* __restrict__ Wih,
    const float* __restrict__ Whh, _Float16* __restrict__ xh,
    _Float16* __restrict__ Wihh, _Float16* __restrict__ Whhh,
    unsigned* __restrict__ flg) {
  long tid = (long)blockIdx.x * blockDim.x + threadIdx.x;
  if (tid < 1024) flg[tid] = 0;
  if (tid < 8388608L) {  // x: 33554432 floats = 8388608 float4
    long f = tid;
    int i4 = (int)(f & 255);          // float4 index within I row
    int s  = (int)((f >> 8) & 511);
    int b  = (int)(f >> 17);
    float4_t v = ((const float4_t*)x)[f];
    half4_t h;
    h[0] = (_Float16)v[0]; h[1] = (_Float16)v[1];
    h[2] = (_Float16)v[2]; h[3] = (_Float16)v[3];
    long dst = ((long)(s * 64 + b) * 1024 + i4 * 4) >> 2;  // half4 units
    ((half4_t*)xh)[dst] = h;
  } else if (tid < 8388608L + 262144L) {
    long f = tid - 8388608L;
    float4_t v = ((const float4_t*)Wih)[f];
    half4_t h;
    h[0] = (_Float16)v[0]; h[1] = (_Float16)v[1];
    h[2] = (_Float16)v[2]; h[3] = (_Float16)v[3];
    ((half4_t*)Wihh)[f] = h;
  } else if (tid < 8388608L + 524288L) {
    long f = tid - 8388608L - 262144L;
    float4_t v = ((const float4_t*)Whh)[f];
    half4_t h;
    h[0] = (_Float16)v[0]; h[1] = (_Float16)v[1];
    h[2] = (_Float16)v[2]; h[3] = (_Float16)v[3];
    ((half4_t*)Whhh)[f] = h;
  }
}

// ============================================================
// Kernel 1: xi = x_h @ W_ih^T + b_ih  (fp16 MFMA, fp32 out -> d_out rows s*B+b)
// ============================================================
__global__ __launch_bounds__(256) void gemm_xi(
    const _Float16* __restrict__ Ap, const _Float16* __restrict__ Bp,
    const float* __restrict__ bias, float* __restrict__ out) {
  __shared__ _Float16 Al[128 * 32];
  __shared__ _Float16 Bl[128 * 32];
  int bid = blockIdx.x;
  int nT = bid & 7, mT = bid >> 3;
  int tid = threadIdx.x;
  int lane = tid & 63, wv = tid >> 6;
  int wm = wv & 1, wn = wv >> 1;
  int nl = lane & 15, quad = lane >> 4;
  long mBase = (long)mT * 128;
  long nBase = (long)nT * 128;
  float4_t acc[4][4] = {};

  for (int k0 = 0; k0 < 1024; k0 += 32) {
    __syncthreads();
#pragma unroll
    for (int c2 = 0; c2 < 2; ++c2) {
      int c = wv * 2 + c2;
      int flat = c * 64 + lane;
      int row = flat >> 2;
      int off = (flat & 3) * 8;
      load_lds16(Ap + (mBase + row) * 1024 + k0 + off, &Al[c * 512]);
      load_lds16(Bp + (nBase + row) * 1024 + k0 + off, &Bl[c * 512]);
    }
    __syncthreads();
    half8 af[4], bf[4];
#pragma unroll
    for (int t = 0; t < 4; ++t) {
      af[t] = *(const half8*)&Al[(wm * 64 + t * 16 + nl) * 32 + quad * 8];
      bf[t] = *(const half8*)&Bl[(wn * 64 + t * 16 + nl) * 32 + quad * 8];
    }
#pragma unroll
    for (int tm = 0; tm < 4; ++tm)
#pragma unroll
      for (int tn = 0; tn < 4; ++tn)
        acc[tm][tn] = __builtin_amdgcn_mfma_f32_16x16x32_f16(
            af[tm], bf[tn], acc[tm][tn], 0, 0, 0);
  }
#pragma unroll
  for (int tm = 0; tm < 4; ++tm) {
    long rowg = mBase + wm * 64 + tm * 16 + quad * 4;
#pragma unroll
    for (int tn = 0; tn < 4; ++tn) {
      long colg = nBase + wn * 64 + tn * 16 + nl;
      float bi = bias[colg];
#pragma unroll
      for (int r = 0; r < 4; ++r)
        out[(rowg + r) * 1024 + colg] = acc[tm][tn][r] + bi;
    }
  }
}

// ============================================================
// Kernel 2: persistent recurrence — ONE group of 32 WGs x 256 thr.
// WG `slice` owns output cols [slice*32, slice*32+32), full M=64 batches.
// W_hh rows for those cols live in 64 KB LDS (XOR-swizzled).
// 4 waves: wm = wv&1 -> batch half (32), wn = wv>>1 -> col group (16).
//
// Sync protocol (NO cache-wide maintenance ops):
//   All cross-WG shared data (hbuf, flags) is accessed exclusively with
//   device-scope (sc1) relaxed atomics -> write-through / read-through the
//   MALL coherence point. Producer: sc1 h-stores, __syncthreads() (per-wave
//   s_waitcnt vmcnt(0) => all sc1 stores acked at MALL), then relaxed sc1
//   flag store. Consumer: relaxed sc1 flag poll, NO acquire fence, relaxed
//   sc1 h-loads. This removes the per-step buffer_wbl2 + buffer_inv (whole-L2
//   writeback/invalidate per WG per step) of the old RELEASE/ACQUIRE scheme,
//   and keeps L2 warm for the xi stream.
// ============================================================
__global__ __launch_bounds__(256) void rnn_rec(
    const _Float16* __restrict__ Whh, const float* __restrict__ bhh,
    float* __restrict__ out, _Float16* __restrict__ hbuf,
    unsigned* __restrict__ flags) {
  __shared__ _Float16 Wl[32 * 1024];  // 64 KB
  const int slice = blockIdx.x;       // 0..31
  const int tid = threadIdx.x;
  const int wv = tid >> 6, lane = tid & 63;
  const int wm = wv & 1, wn = wv >> 1;
  const int nl = lane & 15, quad = lane >> 4;
  const int colbase = slice * 32;

  // preload W_hh rows [colbase, colbase+32), swizzle k8 ^= (n&7) (2-way banks = free)
#pragma unroll 4
  for (int it = 0; it < 32; ++it) {
    int c = it * 256 + tid;          // 8192 half8 chunks
    int n = c >> 7, k8 = c & 127;
    half8 v = *(const half8*)(Whh + (long)(colbase + n) * 1024 + k8 * 8);
    *(half8*)&Wl[n * 1024 + (k8 ^ (n & 7)) * 8] = v;
  }
  __syncthreads();

  const int mycol = colbase + wn * 16 + nl;
  const float bi = bhh[mycol];
  const int swz = (nl & 7);

#pragma unroll 1
  for (int s = 0; s < 512; ++s) {
    // ---- xi prefetch: independent of h, in flight during the poll ----
    float xi[2][4];
#pragma unroll
    for (int t = 0; t < 2; ++t)
#pragma unroll
      for (int r = 0; r < 4; ++r) {
        int bat = wm * 32 + t * 16 + quad * 4 + r;
        xi[t][r] = out[((long)s * 64 + bat) * 1024 + mycol];
      }

    float4_t acc0 = {0.f, 0.f, 0.f, 0.f}, acc1 = {0.f, 0.f, 0.f, 0.f};
    if (s > 0) {
      if (wv == 0) {
        const unsigned fidx = (unsigned)(lane & 31) << 5;  // 128-B stride
        while (true) {
          unsigned f = __hip_atomic_load(&flags[fidx], __ATOMIC_RELAXED,
                                         __HIP_MEMORY_SCOPE_AGENT);
          if (__ballot(f < (unsigned)s) == 0ull) break;
          __builtin_amdgcn_s_sleep(2);
        }
      }
      __syncthreads();
      // no acquire fence: h is read below with device-scope (sc1) loads,
      // which are serviced at the coherence point -> always fresh.
      const unsigned long long* h64 =
          (const unsigned long long*)(hbuf + ((s - 1) & 1) * 65536);
      const int e0 = ((wm * 32 + nl) << 10) + quad * 8;        // halfs
      const int e1 = ((wm * 32 + 16 + nl) << 10) + quad * 8;   // halfs
#pragma unroll 8
      for (int kt = 0; kt < 32; ++kt) {
        half8 bfr = *(const half8*)&Wl[(wn * 16 + nl) * 1024 +
                                       ((kt * 4 + quad) ^ swz) * 8];
        union U { unsigned long long u[2]; half8 h; } u0, u1;
        const int k64 = kt * 8;  // kt*32 halfs = kt*8 u64
        u0.u[0] = __hip_atomic_load(h64 + ((e0 >> 2) + k64), __ATOMIC_RELAXED,
                                    __HIP_MEMORY_SCOPE_AGENT);
        u0.u[1] = __hip_atomic_load(h64 + ((e0 >> 2) + k64 + 1), __ATOMIC_RELAXED,
                                    __HIP_MEMORY_SCOPE_AGENT);
        u1.u[0] = __hip_atomic_load(h64 + ((e1 >> 2) + k64), __ATOMIC_RELAXED,
                                    __HIP_MEMORY_SCOPE_AGENT);
        u1.u[1] = __hip_atomic_load(h64 + ((e1 >> 2) + k64 + 1), __ATOMIC_RELAXED,
                                    __HIP_MEMORY_SCOPE_AGENT);
        acc0 = __builtin_amdgcn_mfma_f32_16x16x32_f16(u0.h, bfr, acc0, 0, 0, 0);
        acc1 = __builtin_amdgcn_mfma_f32_16x16x32_f16(u1.h, bfr, acc1, 0, 0, 0);
      }
    }

    // ---- epilogue: h = tanh(xi + h@Whh^T + bhh); publish hbuf (sc1), flag ----
    float hv[2][4];
    unsigned short* hdst = (unsigned short*)(hbuf + (s & 1) * 65536);
#pragma unroll
    for (int t = 0; t < 2; ++t)
#pragma unroll
      for (int r = 0; r < 4; ++r) {
        int bat = wm * 32 + t * 16 + quad * 4 + r;
        float pre = (t == 0 ? acc0[r] : acc1[r]) + xi[t][r] + bi;
        float e = __expf(2.f * pre);
        float v = 1.f - 2.f / (e + 1.f);
        hv[t][r] = v;
        _Float16 hf = (_Float16)v;
        __hip_atomic_store(hdst + bat * 1024 + mycol,
                           __builtin_bit_cast(unsigned short, hf),
                           __ATOMIC_RELAXED, __HIP_MEMORY_SCOPE_AGENT);
      }
    __syncthreads();  // per-wave s_waitcnt vmcnt(0): all sc1 stores acked @MALL
    if (tid == 0)
      __hip_atomic_store(&flags[(unsigned)slice << 5], (unsigned)(s + 1),
                         __ATOMIC_RELAXED, __HIP_MEMORY_SCOPE_AGENT);
    // out stores off the critical path (not part of the sync protocol)
#pragma unroll
    for (int t = 0; t < 2; ++t)
#pragma unroll
      for (int r = 0; r < 4; ++r) {
        int bat = wm * 32 + t * 16 + quad * 4 + r;
        out[((long)s * 64 + bat) * 1024 + mycol] = hv[t][r];
        if (s == 511)
          out[33554432L + bat * 1024 + mycol] = hv[t][r];
      }
  }
}

// ============================================================
extern "C" void kernel_launch(void* const* d_in, const int* in_sizes, int n_in,
                              void* d_out, int out_size, void* d_ws,
                              size_t ws_size, hipStream_t stream) {
  const float* x   = (const float*)d_in[0];
  const float* Wih = (const float*)d_in[1];
  const float* bih = (const float*)d_in[2];
  const float* Whh = (const float*)d_in[3];
  const float* bhh = (const float*)d_in[4];
  char* ws = (char*)d_ws;
  _Float16* xh   = (_Float16*)(ws + XH_OFF);
  _Float16* Wihh = (_Float16*)(ws + WIH_OFF);
  _Float16* Whhh = (_Float16*)(ws + WHH_OFF);
  _Float16* hbuf = (_Float16*)(ws + HBUF_OFF);
  unsigned* flg  = (unsigned*)(ws + FLG_OFF);
  float* out = (float*)d_out;

  convert_kernel<<<34816, 256, 0, stream>>>(x, Wih, Whh, xh, Wihh, Whhh, flg);
  gemm_xi<<<2048, 256, 0, stream>>>(xh, Wihh, bih, out);
  rnn_rec<<<32, 256, 0, stream>>>(Whhh, bhh, out, hbuf, flg);
}

// Round 2
// 3387.304 us; speedup vs baseline: 2.4198x; 2.4198x over previous
//
#include <hip/hip_runtime.h>
#include <math.h>

// ---- problem constants ----
#define BB 64
#define SS 512
#define II 1024
#define HH 1024

typedef _Float16 half8  __attribute__((ext_vector_type(8)));
typedef _Float16 half4_t __attribute__((ext_vector_type(4)));
typedef float    float4_t __attribute__((ext_vector_type(4)));

// ---- workspace layout (bytes) ----
#define XH_OFF   0u            // fp16 x, (S,B,I) layout: 67108864 B
#define WIH_OFF  67108864u     // fp16 W_ih [H][I]: 2097152 B
#define WHH_OFF  69206016u     // fp16 W_hh [H][H]: 2097152 B
#define HBUF_OFF 71303168u     // fp16 h double buffer [2][64][1024]: 262144 B
#define FLG_OFF  71565312u     // 32 per-WG flags, padded to 128 B stride (4 KB)

__device__ __forceinline__ void load_lds16(const void* g, void* l) {
  __builtin_amdgcn_global_load_lds(
      (const __attribute__((address_space(1))) void*)g,
      (__attribute__((address_space(3))) void*)l, 16, 0, 0);
}

// ============================================================
// Kernel 0: convert x -> fp16 time-major, weights -> fp16, zero flags
// ============================================================
__global__ __launch_bounds__(256) void convert_kernel(
    const float* __restrict__ x, const float* __restrict__ Wih,
    const float* __restrict__ Whh, _Float16* __restrict__ xh,
    _Float16* __restrict__ Wihh, _Float16* __restrict__ Whhh,
    unsigned* __restrict__ flg) {
  long tid = (long)blockIdx.x * blockDim.x + threadIdx.x;
  if (tid < 1024) flg[tid] = 0;
  if (tid < 8388608L) {  // x: 33554432 floats = 8388608 float4
    long f = tid;
    int i4 = (int)(f & 255);          // float4 index within I row
    int s  = (int)((f >> 8) & 511);
    int b  = (int)(f >> 17);
    float4_t v = ((const float4_t*)x)[f];
    half4_t h;
    h[0] = (_Float16)v[0]; h[1] = (_Float16)v[1];
    h[2] = (_Float16)v[2]; h[3] = (_Float16)v[3];
    long dst = ((long)(s * 64 + b) * 1024 + i4 * 4) >> 2;  // half4 units
    ((half4_t*)xh)[dst] = h;
  } else if (tid < 8388608L + 262144L) {
    long f = tid - 8388608L;
    float4_t v = ((const float4_t*)Wih)[f];
    half4_t h;
    h[0] = (_Float16)v[0]; h[1] = (_Float16)v[1];
    h[2] = (_Float16)v[2]; h[3] = (_Float16)v[3];
    ((half4_t*)Wihh)[f] = h;
  } else if (tid < 8388608L + 524288L) {
    long f = tid - 8388608L - 262144L;
    float4_t v = ((const float4_t*)Whh)[f];
    half4_t h;
    h[0] = (_Float16)v[0]; h[1] = (_Float16)v[1];
    h[2] = (_Float16)v[2]; h[3] = (_Float16)v[3];
    ((half4_t*)Whhh)[f] = h;
  }
}

// ============================================================
// Kernel 1: xi = x_h @ W_ih^T + b_ih  (fp16 MFMA, fp32 out -> d_out rows s*B+b)
// ============================================================
__global__ __launch_bounds__(256) void gemm_xi(
    const _Float16* __restrict__ Ap, const _Float16* __restrict__ Bp,
    const float* __restrict__ bias, float* __restrict__ out) {
  __shared__ _Float16 Al[128 * 32];
  __shared__ _Float16 Bl[128 * 32];
  int bid = blockIdx.x;
  int nT = bid & 7, mT = bid >> 3;
  int tid = threadIdx.x;
  int lane = tid & 63, wv = tid >> 6;
  int wm = wv & 1, wn = wv >> 1;
  int nl = lane & 15, quad = lane >> 4;
  long mBase = (long)mT * 128;
  long nBase = (long)nT * 128;
  float4_t acc[4][4] = {};

  for (int k0 = 0; k0 < 1024; k0 += 32) {
    __syncthreads();
#pragma unroll
    for (int c2 = 0; c2 < 2; ++c2) {
      int c = wv * 2 + c2;
      int flat = c * 64 + lane;
      int row = flat >> 2;
      int off = (flat & 3) * 8;
      load_lds16(Ap + (mBase + row) * 1024 + k0 + off, &Al[c * 512]);
      load_lds16(Bp + (nBase + row) * 1024 + k0 + off, &Bl[c * 512]);
    }
    __syncthreads();
    half8 af[4], bf[4];
#pragma unroll
    for (int t = 0; t < 4; ++t) {
      af[t] = *(const half8*)&Al[(wm * 64 + t * 16 + nl) * 32 + quad * 8];
      bf[t] = *(const half8*)&Bl[(wn * 64 + t * 16 + nl) * 32 + quad * 8];
    }
#pragma unroll
    for (int tm = 0; tm < 4; ++tm)
#pragma unroll
      for (int tn = 0; tn < 4; ++tn)
        acc[tm][tn] = __builtin_amdgcn_mfma_f32_16x16x32_f16(
            af[tm], bf[tn], acc[tm][tn], 0, 0, 0);
  }
#pragma unroll
  for (int tm = 0; tm < 4; ++tm) {
    long rowg = mBase + wm * 64 + tm * 16 + quad * 4;
#pragma unroll
    for (int tn = 0; tn < 4; ++tn) {
      long colg = nBase + wn * 64 + tn * 16 + nl;
      float bi = bias[colg];
#pragma unroll
      for (int r = 0; r < 4; ++r)
        out[(rowg + r) * 1024 + colg] = acc[tm][tn][r] + bi;
    }
  }
}

// ============================================================
// Kernel 2: persistent recurrence — ONE group of 32 WGs x 256 thr.
// WG `slice` owns output cols [slice*32, slice*32+32), full M=64 batches.
// W_hh rows for those cols live in 64 KB LDS (XOR-swizzled).
//
// Wave map (NEW): wv = batch quarter. Each wave computes its 16 batches
// x all 32 slice cols (2 n-tiles). Each h row is read by exactly ONE wave
// -> 128 KB coherent h traffic per WG per step (was 256 KB).
//
// Sync protocol (fence-free, wide device-scope accesses):
//   - h publish: LDS-staged 64x32 fp16 tile, then 256 contiguous 16-B
//     global_store_dwordx4 sc0 sc1 (write-through to MALL). The following
//     __syncthreads() emits s_waitcnt vmcnt(0) -> all stores acked at the
//     coherence point before tid0's relaxed device-scope flag store.
//   - consumer: relaxed sc1 flag poll, NO acquire fence; h read as 32
//     back-to-back global_load_dwordx4 sc0 sc1 (L1/L2-bypassing, 128 KB
//     in flight), one s_waitcnt vmcnt(0) + sched_barrier(0) before MFMA.
//   - NO buffer_wbl2 / buffer_inv anywhere; L2 stays warm for xi/out.
// ============================================================
__global__ __launch_bounds__(256, 1) void rnn_rec(
    const _Float16* __restrict__ Whh, const float* __restrict__ bhh,
    float* __restrict__ out, _Float16* __restrict__ hbuf,
    unsigned* __restrict__ flags) {
  __shared__ _Float16 Wl[32 * 1024];   // 64 KB
  __shared__ _Float16 hstage[64 * 32]; // 4 KB publish staging
  const int slice = blockIdx.x;        // 0..31
  const int tid = threadIdx.x;
  const int wv = tid >> 6, lane = tid & 63;
  const int nl = lane & 15, quad = lane >> 4;
  const int colbase = slice * 32;

  // preload W_hh rows [colbase, colbase+32), swizzle k8 ^= (n&7)
#pragma unroll 4
  for (int it = 0; it < 32; ++it) {
    int c = it * 256 + tid;          // 8192 half8 chunks
    int n = c >> 7, k8 = c & 127;
    half8 v = *(const half8*)(Whh + (long)(colbase + n) * 1024 + k8 * 8);
    *(half8*)&Wl[n * 1024 + (k8 ^ (n & 7)) * 8] = v;
  }
  __syncthreads();

  const int mycol0 = colbase + nl;        // n-tile 0
  const int mycol1 = colbase + 16 + nl;   // n-tile 1
  const float bi0 = bhh[mycol0];
  const float bi1 = bhh[mycol1];
  const int swz = (nl & 7);               // same for n and n+16

#pragma unroll 1
  for (int s = 0; s < 512; ++s) {
    // ---- xi prefetch: independent of h, in flight during the poll ----
    float xi0[4], xi1[4];
#pragma unroll
    for (int r = 0; r < 4; ++r) {
      int bat = wv * 16 + quad * 4 + r;
      xi0[r] = out[((long)s * 64 + bat) * 1024 + mycol0];
      xi1[r] = out[((long)s * 64 + bat) * 1024 + mycol1];
    }

    float4_t acc0 = {0.f, 0.f, 0.f, 0.f}, acc1 = {0.f, 0.f, 0.f, 0.f};
    if (s > 0) {
      if (wv == 0) {
        const unsigned fidx = (unsigned)(lane & 31) << 5;  // 128-B stride
        while (true) {
          unsigned f = __hip_atomic_load(&flags[fidx], __ATOMIC_RELAXED,
                                         __HIP_MEMORY_SCOPE_AGENT);
          if (__ballot(f < (unsigned)s) == 0ull) break;
          __builtin_amdgcn_s_sleep(2);
        }
      }
      __syncthreads();  // emits s_waitcnt vmcnt(0): xi + prior stores drained

      // h row for this lane: one row per (wv,nl), k-chunk by quad
      const _Float16* hp = hbuf + ((s - 1) & 1) * 65536 +
                           ((wv * 16 + nl) << 10) + quad * 8;
      float4_t hf[32];
      __builtin_amdgcn_sched_barrier(0);
#pragma unroll
      for (int kt = 0; kt < 32; ++kt)
        asm volatile("global_load_dwordx4 %0, %1, off sc0 sc1"
                     : "=v"(hf[kt]) : "v"(hp + kt * 32));
      asm volatile("s_waitcnt vmcnt(0)" ::: "memory");
      __builtin_amdgcn_sched_barrier(0);  // rule 18: pin MFMAs below the wait
#pragma unroll
      for (int kt = 0; kt < 32; ++kt) {
        half8 a = __builtin_bit_cast(half8, hf[kt]);
        half8 b0 = *(const half8*)&Wl[nl * 1024 + ((kt * 4 + quad) ^ swz) * 8];
        half8 b1 = *(const half8*)&Wl[(16 + nl) * 1024 +
                                      ((kt * 4 + quad) ^ swz) * 8];
        acc0 = __builtin_amdgcn_mfma_f32_16x16x32_f16(a, b0, acc0, 0, 0, 0);
        acc1 = __builtin_amdgcn_mfma_f32_16x16x32_f16(a, b1, acc1, 0, 0, 0);
      }
    }

    // ---- epilogue: h = tanh(xi + h@Whh^T + bhh) -> LDS stage ----
    float hv0[4], hv1[4];
#pragma unroll
    for (int r = 0; r < 4; ++r) {
      int bat = wv * 16 + quad * 4 + r;
      float pre0 = acc0[r] + xi0[r] + bi0;
      float e0 = __expf(2.f * pre0);
      float v0 = 1.f - 2.f / (e0 + 1.f);
      hv0[r] = v0;
      hstage[bat * 32 + nl] = (_Float16)v0;
      float pre1 = acc1[r] + xi1[r] + bi1;
      float e1 = __expf(2.f * pre1);
      float v1 = 1.f - 2.f / (e1 + 1.f);
      hv1[r] = v1;
      hstage[bat * 32 + 16 + nl] = (_Float16)v1;
    }
    __syncthreads();  // hstage complete

    // ---- publish: 4 KB contiguous write-through (one dwordx4 / thread) ----
    {
      int bat = tid >> 2, ch = tid & 3;
      float4_t pv = *(const float4_t*)&hstage[bat * 32 + ch * 8];
      _Float16* dst = hbuf + (s & 1) * 65536 + bat * 1024 + colbase + ch * 8;
      asm volatile("global_store_dwordx4 %0, %1, off sc0 sc1"
                   :: "v"(dst), "v"(pv) : "memory");
    }
    __syncthreads();  // s_waitcnt vmcnt(0): publishes acked at MALL
    if (tid == 0)
      __hip_atomic_store(&flags[(unsigned)slice << 5], (unsigned)(s + 1),
                         __ATOMIC_RELAXED, __HIP_MEMORY_SCOPE_AGENT);

    // ---- out stores off the critical path ----
#pragma unroll
    for (int r = 0; r < 4; ++r) {
      int bat = wv * 16 + quad * 4 + r;
      out[((long)s * 64 + bat) * 1024 + mycol0] = hv0[r];
      out[((long)s * 64 + bat) * 1024 + mycol1] = hv1[r];
      if (s == 511) {
        out[33554432L + bat * 1024 + mycol0] = hv0[r];
        out[33554432L + bat * 1024 + mycol1] = hv1[r];
      }
    }
  }
}

// ============================================================
extern "C" void kernel_launch(void* const* d_in, const int* in_sizes, int n_in,
                              void* d_out, int out_size, void* d_ws,
                              size_t ws_size, hipStream_t stream) {
  const float* x   = (const float*)d_in[0];
  const float* Wih = (const float*)d_in[1];
  const float* bih = (const float*)d_in[2];
  const float* Whh = (const float*)d_in[3];
  const float* bhh = (const float*)d_in[4];
  char* ws = (char*)d_ws;
  _Float16* xh   = (_Float16*)(ws + XH_OFF);
  _Float16* Wihh = (_Float16*)(ws + WIH_OFF);
  _Float16* Whhh = (_Float16*)(ws + WHH_OFF);
  _Float16* hbuf = (_Float16*)(ws + HBUF_OFF);
  unsigned* flg  = (unsigned*)(ws + FLG_OFF);
  float* out = (float*)d_out;

  convert_kernel<<<34816, 256, 0, stream>>>(x, Wih, Whh, xh, Wihh, Whhh, flg);
  gemm_xi<<<2048, 256, 0, stream>>>(xh, Wihh, bih, out);
  rnn_rec<<<32, 256, 0, stream>>>(Whhh, bhh, out, hbuf, flg);
}